// Round 12
// baseline (255.329 us; speedup 1.0000x reference)
//
#include <hip/hip_runtime.h>

// SAGAN self-attention, B=4 C=256 H=W=64 (N=4096), CK=32.
//   f = fw@x+fb, g = gw@x+gb, hv = hw@x+hb         (channel 1x1 convs)
//   s[j,m] = sum_k f[k,j] g[k,m];  L[j] = sum_m exp(s[j,m])
//   sa[c,m]= sum_j hv[c,j] * exp(s[j,m] - ln L[j]);  out = gamma*sa + x
//
// exp2 pipeline: fgT stores f*log2(e); lgL = log2(L); exp(s-lnL) ==
// exp2(s*log2e - log2L) via v_exp_f32 with -log2L folded into MFMA1's C.
//
// ws layout (bytes) — total 10,764,288:
//   fgT  [4][4096][64]  bf16  @ 0         [n][o]: o<32 = f^T*log2e, o>=32 = g^T
//   hv   [4][256][4096] bf16  @ 2097152
//   Lp   [4][4][4096]   f32   @ 10485760  partial L sums (4 m-splits)
//   lgL  [4][4096]      f32   @ 10747904  log2(L)
//
// XCD map (grid%8==0): b=(bid&7)>>1 pins each batch's fgT+hv to one XCD pair L2.

typedef __bf16 bf16x4 __attribute__((ext_vector_type(4)));
typedef __bf16 bf16x8 __attribute__((ext_vector_type(8)));
typedef float  f32x4  __attribute__((ext_vector_type(4)));

static __device__ __forceinline__ bf16x8 frag_cat(bf16x4 lo, bf16x4 hi) {
  bf16x8 r;
  r[0]=lo[0]; r[1]=lo[1]; r[2]=lo[2]; r[3]=lo[3];
  r[4]=hi[0]; r[5]=hi[1]; r[6]=hi[2]; r[7]=hi[3];
  return r;
}
static __device__ __forceinline__ bf16x8 cvt8(f32x4 lo, f32x4 hi) {
  bf16x8 r;
  r[0]=(__bf16)lo[0]; r[1]=(__bf16)lo[1]; r[2]=(__bf16)lo[2]; r[3]=(__bf16)lo[3];
  r[4]=(__bf16)hi[0]; r[5]=(__bf16)hi[1]; r[6]=(__bf16)hi[2]; r[7]=(__bf16)hi[3];
  return r;
}
// kappa k-map (tied to MFMA D output): e -> k = h*4 + (e&3) + 16*(e>>2).
// Free axes (channel contraction): e -> k = h*8 + e (single 16B load).

// ---------------- proj: x read ONCE; block = 64 n-cols x all 320 m-rows ----------
__global__ __launch_bounds__(512, 1) void k_proj(
    const float* __restrict__ fw, const float* __restrict__ gw,
    const float* __restrict__ hw, const float* __restrict__ x,
    const float* __restrict__ fb, const float* __restrict__ gb,
    const float* __restrict__ hb,
    __bf16* __restrict__ fgT, __bf16* __restrict__ hv) {
  __shared__ __bf16 Bs[2][64][40];
  const int bid = blockIdx.x;
  const int b = (bid & 7) >> 1;
  const int n0 = (((bid >> 3) << 1) | (bid & 1)) * 64;
  const int t = threadIdx.x, w = t >> 6, lane = t & 63, r16 = lane & 15, h = lane >> 4;
  const int nsub = w & 1, mq = w >> 1;
  const float* xb = x + (size_t)b * (256 * 4096);
  const float* Wp[5];
  #pragma unroll
  for (int mt = 0; mt < 5; ++mt) {
    const int wrow = mq * 80 + mt * 16 + r16;
    Wp[mt] = wrow < 32 ? (fw + wrow * 256)
           : wrow < 64 ? (gw + (wrow - 32) * 256)
                       : (hw + (wrow - 64) * 256);
  }
  const int kk = t >> 4, nc = (t & 15) * 4;
  f32x4 acc[5][2] = {};
  {
    f32x4 xv = *(const f32x4*)&xb[(size_t)kk * 4096 + n0 + nc];
    Bs[0][nc + 0][kk] = (__bf16)xv[0]; Bs[0][nc + 1][kk] = (__bf16)xv[1];
    Bs[0][nc + 2][kk] = (__bf16)xv[2]; Bs[0][nc + 3][kk] = (__bf16)xv[3];
  }
  __syncthreads();
  for (int ks = 0; ks < 8; ++ks) {
    const int cur = ks & 1;
    f32x4 xn;
    if (ks < 7) xn = *(const f32x4*)&xb[(size_t)((ks + 1) * 32 + kk) * 4096 + n0 + nc];
    bf16x8 bf0 = *(const bf16x8*)&Bs[cur][nsub * 32 + r16][h * 8];
    bf16x8 bf1 = *(const bf16x8*)&Bs[cur][nsub * 32 + 16 + r16][h * 8];
    #pragma unroll
    for (int mt = 0; mt < 5; ++mt) {
      f32x4 wlo = *(const f32x4*)(Wp[mt] + ks * 32 + h * 8);
      f32x4 whi = *(const f32x4*)(Wp[mt] + ks * 32 + h * 8 + 4);
      bf16x8 af = cvt8(wlo, whi);
      acc[mt][0] = __builtin_amdgcn_mfma_f32_16x16x32_bf16(af, bf0, acc[mt][0], 0, 0, 0);
      acc[mt][1] = __builtin_amdgcn_mfma_f32_16x16x32_bf16(af, bf1, acc[mt][1], 0, 0, 0);
    }
    if (ks < 7) {
      const int nxt = cur ^ 1;
      Bs[nxt][nc + 0][kk] = (__bf16)xn[0]; Bs[nxt][nc + 1][kk] = (__bf16)xn[1];
      Bs[nxt][nc + 2][kk] = (__bf16)xn[2]; Bs[nxt][nc + 3][kk] = (__bf16)xn[3];
    }
    __syncthreads();
  }
  #pragma unroll
  for (int mt = 0; mt < 5; ++mt) {
    #pragma unroll
    for (int nt = 0; nt < 2; ++nt) {
      const int nn = n0 + nsub * 32 + nt * 16 + r16;
      #pragma unroll
      for (int r = 0; r < 4; ++r) {
        const int row = mq * 80 + mt * 16 + h * 4 + r;  // C/D: row=(lane>>4)*4+reg
        const float bias = row < 32 ? fb[row] : (row < 64 ? gb[row - 32] : hb[row - 64]);
        float val = acc[mt][nt][r] + bias;
        if (row < 32) val *= 1.44269504089f;            // f * log2(e)
        if (row < 64) fgT[((size_t)b * 4096 + nn) * 64 + row] = (__bf16)val;
        else          hv[((size_t)b * 256 + (row - 64)) * 4096 + nn] = (__bf16)val;
      }
    }
  }
}

// ---------------- pass1: L[i] = sum_m exp2(f'_i . g_m)  (partial, m-quarter) ----
__global__ __launch_bounds__(256) void k_pass1(const __bf16* __restrict__ fgT,
                                               float* __restrict__ Lp) {
  const int bid = blockIdx.x;
  const int b = (bid & 7) >> 1;
  const int sub = ((bid >> 3) << 1) | (bid & 1);
  const int ms = sub >> 6, ib = sub & 63;
  const int w = threadIdx.x >> 6, lane = threadIdx.x & 63, r16 = lane & 15, h = lane >> 4;
  const int ibase = ib * 64 + w * 16;
  const __bf16* fg = fgT + (size_t)b * (4096 * 64);
  const bf16x8 afrag = *(const bf16x8*)(fg + (size_t)(ibase + r16) * 64 + h * 8);
  const f32x4 zero = {};
  float ls0 = 0.f, ls1 = 0.f, ls2 = 0.f, ls3 = 0.f;
  for (int mt = 0; mt < 64; mt += 2) {
    const int mb = ms * 1024 + mt * 16;
    bf16x8 g0 = *(const bf16x8*)(fg + (size_t)(mb + r16) * 64 + 32 + h * 8);
    bf16x8 g1 = *(const bf16x8*)(fg + (size_t)(mb + 16 + r16) * 64 + 32 + h * 8);
    f32x4 d0 = __builtin_amdgcn_mfma_f32_16x16x32_bf16(afrag, g0, zero, 0, 0, 0);
    f32x4 d1 = __builtin_amdgcn_mfma_f32_16x16x32_bf16(afrag, g1, zero, 0, 0, 0);
    ls0 += __builtin_amdgcn_exp2f(d0[0]) + __builtin_amdgcn_exp2f(d1[0]);
    ls1 += __builtin_amdgcn_exp2f(d0[1]) + __builtin_amdgcn_exp2f(d1[1]);
    ls2 += __builtin_amdgcn_exp2f(d0[2]) + __builtin_amdgcn_exp2f(d1[2]);
    ls3 += __builtin_amdgcn_exp2f(d0[3]) + __builtin_amdgcn_exp2f(d1[3]);
  }
  #pragma unroll
  for (int off = 1; off < 16; off <<= 1) {
    ls0 += __shfl_xor(ls0, off); ls1 += __shfl_xor(ls1, off);
    ls2 += __shfl_xor(ls2, off); ls3 += __shfl_xor(ls3, off);
  }
  if (r16 == 0) {
    f32x4 o = {ls0, ls1, ls2, ls3};
    *(f32x4*)&Lp[(size_t)(b * 4 + ms) * 4096 + ibase + h * 4] = o;
  }
}

// ---------------- lfin: lgL[b][j] = log2(sum of 4 Lp partials) ----------------
__global__ __launch_bounds__(256) void k_lfin(const float* __restrict__ Lp,
                                              float* __restrict__ lgL) {
  const int e = (blockIdx.x * 256 + threadIdx.x) * 4;
  const int b = e >> 12, j = e & 4095;
  const float* lp = Lp + (size_t)b * (4 * 4096) + j;
  f32x4 L = *(const f32x4*)lp;
  L += *(const f32x4*)(lp + 4096);
  L += *(const f32x4*)(lp + 8192);
  L += *(const f32x4*)(lp + 12288);
  f32x4 o = {__builtin_amdgcn_logf(L[0]), __builtin_amdgcn_logf(L[1]),
             __builtin_amdgcn_logf(L[2]), __builtin_amdgcn_logf(L[3])};
  *(f32x4*)&lgL[b * 4096 + j] = o;
}

// ---------------- pass2: BARRIER-FREE wave-private pipeline ----------------
// R10 lesson: per-iter __syncthreads convoy is the binder (73% occ, 11% MFMA).
// Block = 64c x 64m (grid 1024), 4 waves = (msub 32m, jh 32j). Each wave stages
// its OWN 64c x 32j w-chunk into PRIVATE LDS (2 x 4KB dbuf) -> reads only its
// own writes -> intra-wave vmcnt/lgkmcnt ordering, ZERO barriers in the loop.
// Swizzle (alignment-safe): in-row byte off ^= 16*((row>>1)&3). Enumerated:
// b128 writes uniform 32B/bank (floor), kappa b64 reads exactly 2-way (free).
// MFMA1 D (rows j, cols m) after exp2 is IN-REGISTER the B-frag of MFMA2 under
// the kappa map k = h*4 + (e&3) + 16*(e>>2).
__global__ __launch_bounds__(256, 4) void k_pass2(const __bf16* __restrict__ fgT,
    const __bf16* __restrict__ hv, const float* __restrict__ lgL,
    const float* __restrict__ x, const float* __restrict__ gamma,
    float* __restrict__ out) {
  __shared__ char wS[4][8192];   // per-wave: 2 x 4KB buffers; epilogue scratch
  const int bid = blockIdx.x;
  const int b = (bid & 7) >> 1;                     // XCD pair per batch
  const int cq = (bid >> 3) & 3;                    // c-quarter
  const int mblk = ((bid >> 5) << 1) | (bid & 1);   // 0..63
  const int t = threadIdx.x, w = t >> 6, lane = t & 63, r16 = lane & 15, h = lane >> 4;
  const int jh = w & 1, msub = w >> 1;
  const int mbase = mblk * 64 + msub * 32;
  const __bf16* fg = fgT + (size_t)b * (4096 * 64);
  const __bf16* wb = hv + ((size_t)b * 256 + cq * 64) * 4096;
  const float* lgb = lgL + b * 4096;
  // gfrags: MFMA1 B operands (contiguous channel map), invariant over j
  const bf16x8 gf0 = *(const bf16x8*)(fg + (size_t)(mbase + r16) * 64 + 32 + h * 8);
  const bf16x8 gf1 = *(const bf16x8*)(fg + (size_t)(mbase + 16 + r16) * 64 + 32 + h * 8);
  // staging lane geometry: instr i covers row 16i+r16, 16B chunk q=lane>>4
  const int q = lane >> 4;
  const int swz = 16 * ((r16 >> 1) & 3);            // shared read/write XOR
  const __bf16* gs0 = wb + (size_t)(r16)      * 4096 + q * 8;
  const __bf16* gs1 = wb + (size_t)(16 + r16) * 4096 + q * 8;
  const __bf16* gs2 = wb + (size_t)(32 + r16) * 4096 + q * 8;
  const __bf16* gs3 = wb + (size_t)(48 + r16) * 4096 + q * 8;
  char* const wbase = &wS[w][0];
  const int woff = r16 * 64 + ((q * 16) ^ swz);     // + 1024*i per instr
  const int ro0 = (8 * h) ^ swz, ro1 = (32 + 8 * h) ^ swz;
  const int h8 = h * 8;

  f32x4 acc[4][2] = {};

  // prologue: stage chunk 0 into buf0; f frags + lg2L for chunk 0
  int j0 = jh * 32;
  {
    uint4 a0 = *(const uint4*)(gs0 + j0);
    uint4 a1 = *(const uint4*)(gs1 + j0);
    uint4 a2 = *(const uint4*)(gs2 + j0);
    uint4 a3 = *(const uint4*)(gs3 + j0);
    *(uint4*)(wbase + woff +    0) = a0;
    *(uint4*)(wbase + woff + 1024) = a1;
    *(uint4*)(wbase + woff + 2048) = a2;
    *(uint4*)(wbase + woff + 3072) = a3;
  }
  bf16x8 fq0 = *(const bf16x8*)(fg + (size_t)(j0 + r16) * 64 + h8);
  bf16x8 fq1 = *(const bf16x8*)(fg + (size_t)(j0 + 16 + r16) * 64 + h8);
  f32x4 lg0 = *(const f32x4*)(lgb + j0 + 4 * h);
  f32x4 lg1 = *(const f32x4*)(lgb + j0 + 16 + 4 * h);

  for (int it = 0; it < 64; ++it) {
    const int cur = it & 1;
    char* const curb = wbase + cur * 4096;
    const int jn = j0 + 64;                         // next chunk for this wave
    uint4 pa0, pa1, pa2, pa3; bf16x8 nf0, nf1; f32x4 nl0, nl1;
    if (it < 63) {   // issue next-chunk loads early; latency hides under compute
      pa0 = *(const uint4*)(gs0 + jn);
      pa1 = *(const uint4*)(gs1 + jn);
      pa2 = *(const uint4*)(gs2 + jn);
      pa3 = *(const uint4*)(gs3 + jn);
      nf0 = *(const bf16x8*)(fg + (size_t)(jn + r16) * 64 + h8);
      nf1 = *(const bf16x8*)(fg + (size_t)(jn + 16 + r16) * 64 + h8);
      nl0 = *(const f32x4*)(lgb + jn + 4 * h);
      nl1 = *(const f32x4*)(lgb + jn + 16 + 4 * h);
    }
    // MFMA1 x4 with C = -lg2L, then exp2 -> ef0 (m-tile0), ef1 (m-tile1)
    f32x4 d0 = __builtin_amdgcn_mfma_f32_16x16x32_bf16(fq0, gf0, -lg0, 0, 0, 0);
    f32x4 d1 = __builtin_amdgcn_mfma_f32_16x16x32_bf16(fq1, gf0, -lg1, 0, 0, 0);
    f32x4 d2 = __builtin_amdgcn_mfma_f32_16x16x32_bf16(fq0, gf1, -lg0, 0, 0, 0);
    f32x4 d3 = __builtin_amdgcn_mfma_f32_16x16x32_bf16(fq1, gf1, -lg1, 0, 0, 0);
    bf16x8 ef0, ef1;
    #pragma unroll
    for (int r = 0; r < 4; ++r) {
      ef0[r]     = (__bf16)__builtin_amdgcn_exp2f(d0[r]);
      ef0[4 + r] = (__bf16)__builtin_amdgcn_exp2f(d1[r]);
      ef1[r]     = (__bf16)__builtin_amdgcn_exp2f(d2[r]);
      ef1[4 + r] = (__bf16)__builtin_amdgcn_exp2f(d3[r]);
    }
    // MFMA2: 4 c-tiles from OWN LDS chunk; one w-frag feeds both m-accs
    #pragma unroll
    for (int ct = 0; ct < 4; ++ct) {
      const char* rp = curb + ct * 1024 + r16 * 64;
      bf16x8 a = frag_cat(*(const bf16x4*)(rp + ro0), *(const bf16x4*)(rp + ro1));
      acc[ct][0] = __builtin_amdgcn_mfma_f32_16x16x32_bf16(a, ef0, acc[ct][0], 0, 0, 0);
      acc[ct][1] = __builtin_amdgcn_mfma_f32_16x16x32_bf16(a, ef1, acc[ct][1], 0, 0, 0);
    }
    if (it < 63) {   // write next chunk into own other buffer (no barrier!)
      char* const nb = wbase + (cur ^ 1) * 4096;
      *(uint4*)(nb + woff +    0) = pa0;
      *(uint4*)(nb + woff + 1024) = pa1;
      *(uint4*)(nb + woff + 2048) = pa2;
      *(uint4*)(nb + woff + 3072) = pa3;
      fq0 = nf0; fq1 = nf1; lg0 = nl0; lg1 = nl1;
      j0 = jn;
    }
  }

  // epilogue: single barrier; jh=1 dumps partials into wS (dead), jh=0 adds.
  __syncthreads();
  float* red = (float*)wS;
  const int region = msub * 2048;                   // 2 regions x 8KB (floats)
  if (jh == 1) {
    #pragma unroll
    for (int ct = 0; ct < 4; ++ct)
      #pragma unroll
      for (int mt = 0; mt < 2; ++mt)
        *(f32x4*)&red[region + ((ct * 2 + mt) * 64 + lane) * 4] = acc[ct][mt];
  }
  __syncthreads();
  if (jh == 0) {
    const float gm = gamma[0];
    const float* xb = x + (size_t)b * (256 * 4096);
    float* ob = out + (size_t)b * (256 * 4096);
    #pragma unroll
    for (int ct = 0; ct < 4; ++ct) {
      #pragma unroll
      for (int mt = 0; mt < 2; ++mt) {
        f32x4 o = *(const f32x4*)&red[region + ((ct * 2 + mt) * 64 + lane) * 4];
        o += acc[ct][mt];
        #pragma unroll
        for (int r = 0; r < 4; ++r) {
          const int c = cq * 64 + ct * 16 + h * 4 + r;
          const size_t idx = (size_t)c * 4096 + (mbase + mt * 16 + r16);
          ob[idx] = gm * o[r] + xb[idx];
        }
      }
    }
  }
}

extern "C" void kernel_launch(void* const* d_in, const int* in_sizes, int n_in,
                              void* d_out, int out_size, void* d_ws, size_t ws_size,
                              hipStream_t stream) {
  const float* x     = (const float*)d_in[0];
  const float* fw    = (const float*)d_in[1];
  const float* fb    = (const float*)d_in[2];
  const float* gw    = (const float*)d_in[3];
  const float* gb    = (const float*)d_in[4];
  const float* hw    = (const float*)d_in[5];
  const float* hb    = (const float*)d_in[6];
  const float* gamma = (const float*)d_in[7];
  float* out = (float*)d_out;

  char* wsb = (char*)d_ws;
  __bf16* fgT = (__bf16*)(wsb);
  __bf16* hv  = (__bf16*)(wsb + 2097152);
  float*  Lp  = (float*) (wsb + 10485760);
  float*  lgL = (float*) (wsb + 10747904);

  k_proj<<<dim3(256), dim3(512), 0, stream>>>(fw, gw, hw, x, fb, gb, hb, fgT, hv);
  k_pass1<<<dim3(1024), dim3(256), 0, stream>>>(fgT, Lp);
  k_lfin<<<dim3(16), dim3(256), 0, stream>>>(Lp, lgL);
  k_pass2<<<dim3(1024), dim3(256), 0, stream>>>(fgT, hv, lgL, x, gamma, out);
}

// Round 13
// 153.334 us; speedup vs baseline: 1.6652x; 1.6652x over previous
//
#include <hip/hip_runtime.h>

// SAGAN self-attention, B=4 C=256 H=W=64 (N=4096), CK=32.
//   f = fw@x+fb, g = gw@x+gb, hv = hw@x+hb         (channel 1x1 convs)
//   s[j,m] = sum_k f[k,j] g[k,m];  L[j] = sum_m exp(s[j,m])
//   w[c,j] = hv[c,j]/L[j];  sa[c,m] = sum_j w[c,j] exp(s[j,m]);  out = gamma*sa+x
//
// exp2 pipeline: fgT stores f*log2(e) -> exp2(f'.g) == exp(s) via bare v_exp_f32.
// R11 lesson: in-loop lnL fold always lost to the one-time wdiv pass (R4=102 vs
// R5=126 vs R7=110). This round: R7 geometry + wdiv restored + C=0 MFMA1.
//
// ws layout (bytes) — total 10,747,904:
//   fgT  [4][4096][64]  bf16  @ 0         [n][o]: o<32 = f^T*log2e, o>=32 = g^T
//   hv/w [4][256][4096] bf16  @ 2097152   proj writes hv; wdiv -> w in place
//   Lp   [4][4][4096]   f32   @ 10485760  partial L sums (4 m-splits)
//
// XCD map (grid%8==0): b=(bid&7)>>1 pins each batch's fgT+w to one XCD pair L2.

typedef __bf16 bf16x4 __attribute__((ext_vector_type(4)));
typedef __bf16 bf16x8 __attribute__((ext_vector_type(8)));
typedef float  f32x4  __attribute__((ext_vector_type(4)));

static __device__ __forceinline__ bf16x8 frag_cat(bf16x4 lo, bf16x4 hi) {
  bf16x8 r;
  r[0]=lo[0]; r[1]=lo[1]; r[2]=lo[2]; r[3]=lo[3];
  r[4]=hi[0]; r[5]=hi[1]; r[6]=hi[2]; r[7]=hi[3];
  return r;
}
static __device__ __forceinline__ bf16x8 cvt8(f32x4 lo, f32x4 hi) {
  bf16x8 r;
  r[0]=(__bf16)lo[0]; r[1]=(__bf16)lo[1]; r[2]=(__bf16)lo[2]; r[3]=(__bf16)lo[3];
  r[4]=(__bf16)hi[0]; r[5]=(__bf16)hi[1]; r[6]=(__bf16)hi[2]; r[7]=(__bf16)hi[3];
  return r;
}
// kappa k-map (tied to MFMA D output): e -> k = h*4 + (e&3) + 16*(e>>2).
// Free axes (channel contraction): e -> k = h*8 + e (single 16B load).

// ---------------- proj: x read ONCE; block = 64 n-cols x all 320 m-rows ----------
__global__ __launch_bounds__(512, 1) void k_proj(
    const float* __restrict__ fw, const float* __restrict__ gw,
    const float* __restrict__ hw, const float* __restrict__ x,
    const float* __restrict__ fb, const float* __restrict__ gb,
    const float* __restrict__ hb,
    __bf16* __restrict__ fgT, __bf16* __restrict__ hv) {
  __shared__ __bf16 Bs[2][64][40];
  const int bid = blockIdx.x;
  const int b = (bid & 7) >> 1;
  const int n0 = (((bid >> 3) << 1) | (bid & 1)) * 64;
  const int t = threadIdx.x, w = t >> 6, lane = t & 63, r16 = lane & 15, h = lane >> 4;
  const int nsub = w & 1, mq = w >> 1;
  const float* xb = x + (size_t)b * (256 * 4096);
  const float* Wp[5];
  #pragma unroll
  for (int mt = 0; mt < 5; ++mt) {
    const int wrow = mq * 80 + mt * 16 + r16;
    Wp[mt] = wrow < 32 ? (fw + wrow * 256)
           : wrow < 64 ? (gw + (wrow - 32) * 256)
                       : (hw + (wrow - 64) * 256);
  }
  const int kk = t >> 4, nc = (t & 15) * 4;
  f32x4 acc[5][2] = {};
  {
    f32x4 xv = *(const f32x4*)&xb[(size_t)kk * 4096 + n0 + nc];
    Bs[0][nc + 0][kk] = (__bf16)xv[0]; Bs[0][nc + 1][kk] = (__bf16)xv[1];
    Bs[0][nc + 2][kk] = (__bf16)xv[2]; Bs[0][nc + 3][kk] = (__bf16)xv[3];
  }
  __syncthreads();
  for (int ks = 0; ks < 8; ++ks) {
    const int cur = ks & 1;
    f32x4 xn;
    if (ks < 7) xn = *(const f32x4*)&xb[(size_t)((ks + 1) * 32 + kk) * 4096 + n0 + nc];
    bf16x8 bf0 = *(const bf16x8*)&Bs[cur][nsub * 32 + r16][h * 8];
    bf16x8 bf1 = *(const bf16x8*)&Bs[cur][nsub * 32 + 16 + r16][h * 8];
    #pragma unroll
    for (int mt = 0; mt < 5; ++mt) {
      f32x4 wlo = *(const f32x4*)(Wp[mt] + ks * 32 + h * 8);
      f32x4 whi = *(const f32x4*)(Wp[mt] + ks * 32 + h * 8 + 4);
      bf16x8 af = cvt8(wlo, whi);
      acc[mt][0] = __builtin_amdgcn_mfma_f32_16x16x32_bf16(af, bf0, acc[mt][0], 0, 0, 0);
      acc[mt][1] = __builtin_amdgcn_mfma_f32_16x16x32_bf16(af, bf1, acc[mt][1], 0, 0, 0);
    }
    if (ks < 7) {
      const int nxt = cur ^ 1;
      Bs[nxt][nc + 0][kk] = (__bf16)xn[0]; Bs[nxt][nc + 1][kk] = (__bf16)xn[1];
      Bs[nxt][nc + 2][kk] = (__bf16)xn[2]; Bs[nxt][nc + 3][kk] = (__bf16)xn[3];
    }
    __syncthreads();
  }
  #pragma unroll
  for (int mt = 0; mt < 5; ++mt) {
    #pragma unroll
    for (int nt = 0; nt < 2; ++nt) {
      const int nn = n0 + nsub * 32 + nt * 16 + r16;
      #pragma unroll
      for (int r = 0; r < 4; ++r) {
        const int row = mq * 80 + mt * 16 + h * 4 + r;  // C/D: row=(lane>>4)*4+reg
        const float bias = row < 32 ? fb[row] : (row < 64 ? gb[row - 32] : hb[row - 64]);
        float val = acc[mt][nt][r] + bias;
        if (row < 32) val *= 1.44269504089f;            // f * log2(e)
        if (row < 64) fgT[((size_t)b * 4096 + nn) * 64 + row] = (__bf16)val;
        else          hv[((size_t)b * 256 + (row - 64)) * 4096 + nn] = (__bf16)val;
      }
    }
  }
}

// ---------------- pass1: L[i] = sum_m exp2(f'_i . g_m)  (partial, m-quarter) ----
__global__ __launch_bounds__(256) void k_pass1(const __bf16* __restrict__ fgT,
                                               float* __restrict__ Lp) {
  const int bid = blockIdx.x;
  const int b = (bid & 7) >> 1;
  const int sub = ((bid >> 3) << 1) | (bid & 1);
  const int ms = sub >> 6, ib = sub & 63;
  const int w = threadIdx.x >> 6, lane = threadIdx.x & 63, r16 = lane & 15, h = lane >> 4;
  const int ibase = ib * 64 + w * 16;
  const __bf16* fg = fgT + (size_t)b * (4096 * 64);
  const bf16x8 afrag = *(const bf16x8*)(fg + (size_t)(ibase + r16) * 64 + h * 8);
  const f32x4 zero = {};
  float ls0 = 0.f, ls1 = 0.f, ls2 = 0.f, ls3 = 0.f;
  for (int mt = 0; mt < 64; mt += 2) {
    const int mb = ms * 1024 + mt * 16;
    bf16x8 g0 = *(const bf16x8*)(fg + (size_t)(mb + r16) * 64 + 32 + h * 8);
    bf16x8 g1 = *(const bf16x8*)(fg + (size_t)(mb + 16 + r16) * 64 + 32 + h * 8);
    f32x4 d0 = __builtin_amdgcn_mfma_f32_16x16x32_bf16(afrag, g0, zero, 0, 0, 0);
    f32x4 d1 = __builtin_amdgcn_mfma_f32_16x16x32_bf16(afrag, g1, zero, 0, 0, 0);
    ls0 += __builtin_amdgcn_exp2f(d0[0]) + __builtin_amdgcn_exp2f(d1[0]);
    ls1 += __builtin_amdgcn_exp2f(d0[1]) + __builtin_amdgcn_exp2f(d1[1]);
    ls2 += __builtin_amdgcn_exp2f(d0[2]) + __builtin_amdgcn_exp2f(d1[2]);
    ls3 += __builtin_amdgcn_exp2f(d0[3]) + __builtin_amdgcn_exp2f(d1[3]);
  }
  #pragma unroll
  for (int off = 1; off < 16; off <<= 1) {
    ls0 += __shfl_xor(ls0, off); ls1 += __shfl_xor(ls1, off);
    ls2 += __shfl_xor(ls2, off); ls3 += __shfl_xor(ls3, off);
  }
  if (r16 == 0) {
    f32x4 o = {ls0, ls1, ls2, ls3};
    *(f32x4*)&Lp[(size_t)(b * 4 + ms) * 4096 + ibase + h * 4] = o;
  }
}

// ---------------- wdiv: w = bf16(hv / L), in place, XCD-pinned ----------------
__global__ __launch_bounds__(256) void k_wdiv(__bf16* __restrict__ hv,
                                              const float* __restrict__ Lp) {
  const int bid = blockIdx.x;
  const int b = (bid & 7) >> 1;
  const int chunk = ((bid >> 3) << 1) | (bid & 1);  // 0..63
  const int base = b * 1048576 + chunk * 16384;     // base % 4096 == 0
  for (int i = threadIdx.x * 4; i < 16384; i += 1024) {
    const int e = base + i;
    const int j = i & 4095;
    bf16x4 h4 = *(const bf16x4*)(hv + e);
    const float* lp = Lp + (size_t)b * (4 * 4096) + j;
    f32x4 L = *(const f32x4*)lp;
    L += *(const f32x4*)(lp + 4096);
    L += *(const f32x4*)(lp + 8192);
    L += *(const f32x4*)(lp + 12288);
    bf16x4 o;
    o[0] = (__bf16)((float)h4[0] / L[0]); o[1] = (__bf16)((float)h4[1] / L[1]);
    o[2] = (__bf16)((float)h4[2] / L[2]); o[3] = (__bf16)((float)h4[3] / L[3]);
    *(bf16x4*)(hv + e) = o;
  }
}

// ---------------- pass2: sa[c,m] = sum_j w[c,j] exp2(f'.g); out=gm*sa+x ------
// R7 geometry (best measured): 1024 blocks x 256 threads (4 blocks/CU), block =
// 64c x 64m, waves = (msub 32m, jh 32j), j-tile 64, barrier per iter.
// LDS [2][64][64] bf16 swizzled (byte ^= 16*(row&7)): bank-enumerated, reads
// exactly 4 lanes/bank-pair (b64 floor), writes 8/bank (b128 floor).
// Changes vs R7: no lnL loads (wdiv pre-divides), MFMA1 C=0, bare exp2.
// MFMA1 D (rows j, cols m) after exp2 is IN-REGISTER the B-frag of MFMA2 under
// the kappa map k = h*4 + (e&3) + 16*(e>>2).
__global__ __launch_bounds__(256, 4) void k_pass2(const __bf16* __restrict__ fgT,
    const __bf16* __restrict__ wbf, const float* __restrict__ x,
    const float* __restrict__ gamma, float* __restrict__ out) {
  __shared__ __bf16 wS[2][64][64];   // 16,384 B, swizzled
  const int bid = blockIdx.x;
  const int b = (bid & 7) >> 1;                     // XCD pair per batch
  const int cq = (bid >> 3) & 3;                    // c-quarter: rows cq*64..+63
  const int mblk = ((bid >> 5) << 1) | (bid & 1);   // 0..63
  const int t = threadIdx.x, w = t >> 6, lane = t & 63, r16 = lane & 15, h = lane >> 4;
  const int jh = w & 1, msub = w >> 1;
  const int mbase = mblk * 64 + msub * 32;
  const __bf16* fg = fgT + (size_t)b * (4096 * 64);
  const __bf16* wb = wbf + ((size_t)b * 256 + cq * 64) * 4096;
  // gfrags: MFMA1 B operands (contiguous channel map), invariant over j
  const bf16x8 gf0 = *(const bf16x8*)(fg + (size_t)(mbase + r16) * 64 + 32 + h * 8);
  const bf16x8 gf1 = *(const bf16x8*)(fg + (size_t)(mbase + 16 + r16) * 64 + 32 + h * 8);
  // staging: thread t covers row t>>2 (of 64), 16 j-elems (32B) at (t&3)*16
  const int srow = t >> 2, q = t & 3;
  const int sw = (srow & 7) << 4;                   // write-side XOR
  const __bf16* sgsrc = wb + (size_t)srow * 4096 + q * 16;
  char* sb0 = (char*)&wS[0][srow][0];
  char* sb1 = (char*)&wS[1][srow][0];
  const int c32 = q * 32;
  const int rsw = (r16 & 7) << 4;                   // read-side XOR
  const int jh64 = jh * 64, h8 = h * 8;
  const int jwave = jh * 32;                        // wave's j-offset in tile
  const f32x4 zero = {};

  f32x4 acc[4] = {};
  f32x4 acc2[4] = {};                               // second m-tile (msub covers 32m)

  // prologue: stage tile 0, load f frags (own jh half) for tile 0
  *(uint4*)(sb0 + ((c32 +  0) ^ sw)) = *(const uint4*)(sgsrc);
  *(uint4*)(sb0 + ((c32 + 16) ^ sw)) = *(const uint4*)(sgsrc + 8);
  bf16x8 fq0 = *(const bf16x8*)(fg + (size_t)(jwave + r16) * 64 + h8);
  bf16x8 fq1 = *(const bf16x8*)(fg + (size_t)(jwave + 16 + r16) * 64 + h8);
  __syncthreads();

  for (int it = 0; it < 64; ++it) {
    const int cur = it & 1;
    const int jbn = (it + 1) * 64;
    uint4 pw0, pw1; bf16x8 nf0, nf1;
    if (it < 63) {   // issue next-tile global loads early (L2-hot, hide under compute)
      pw0 = *(const uint4*)(sgsrc + jbn);
      pw1 = *(const uint4*)(sgsrc + jbn + 8);
      nf0 = *(const bf16x8*)(fg + (size_t)(jbn + jwave + r16) * 64 + h8);
      nf1 = *(const bf16x8*)(fg + (size_t)(jbn + jwave + 16 + r16) * 64 + h8);
    }
    // MFMA1 x4 (two m-subtiles x two kappa j-slices), exp2 -> ef0/ef1
    f32x4 d0 = __builtin_amdgcn_mfma_f32_16x16x32_bf16(fq0, gf0, zero, 0, 0, 0);
    f32x4 d1 = __builtin_amdgcn_mfma_f32_16x16x32_bf16(fq1, gf0, zero, 0, 0, 0);
    f32x4 d2 = __builtin_amdgcn_mfma_f32_16x16x32_bf16(fq0, gf1, zero, 0, 0, 0);
    f32x4 d3 = __builtin_amdgcn_mfma_f32_16x16x32_bf16(fq1, gf1, zero, 0, 0, 0);
    bf16x8 ef0, ef1;
    #pragma unroll
    for (int r = 0; r < 4; ++r) {
      ef0[r]     = (__bf16)__builtin_amdgcn_exp2f(d0[r]);
      ef0[4 + r] = (__bf16)__builtin_amdgcn_exp2f(d1[r]);
      ef1[r]     = (__bf16)__builtin_amdgcn_exp2f(d2[r]);
      ef1[4 + r] = (__bf16)__builtin_amdgcn_exp2f(d3[r]);
    }
    // MFMA2: 4 c-tiles; one w-frag feeds both m-accumulators
    #pragma unroll
    for (int ct = 0; ct < 4; ++ct) {
      const char* rp = (const char*)&wS[cur][ct * 16 + r16][0];
      bf16x8 a = frag_cat(*(const bf16x4*)(rp + ((jh64 + h8) ^ rsw)),
                          *(const bf16x4*)(rp + ((jh64 + h8 + 32) ^ rsw)));
      acc[ct]  = __builtin_amdgcn_mfma_f32_16x16x32_bf16(a, ef0, acc[ct],  0, 0, 0);
      acc2[ct] = __builtin_amdgcn_mfma_f32_16x16x32_bf16(a, ef1, acc2[ct], 0, 0, 0);
    }
    if (it < 63) {   // write next tile into the other buffer
      char* sd = cur ? sb0 : sb1;
      *(uint4*)(sd + ((c32 +  0) ^ sw)) = pw0;
      *(uint4*)(sd + ((c32 + 16) ^ sw)) = pw1;
      fq0 = nf0; fq1 = nf1;
    }
    __syncthreads();
  }

  // jh reduction: jh=1 waves dump partials into wS (dead), jh=0 adds + epilogue.
  float* red = (float*)wS;
  const int region = msub * 2048;                   // 2 regions x 8KB (floats)
  if (jh == 1) {
    #pragma unroll
    for (int ct = 0; ct < 4; ++ct) {
      *(f32x4*)&red[region + ((ct * 2 + 0) * 64 + lane) * 4] = acc[ct];
      *(f32x4*)&red[region + ((ct * 2 + 1) * 64 + lane) * 4] = acc2[ct];
    }
  }
  __syncthreads();
  if (jh == 0) {
    const float gm = gamma[0];
    const float* xb = x + (size_t)b * (256 * 4096);
    float* ob = out + (size_t)b * (256 * 4096);
    #pragma unroll
    for (int ct = 0; ct < 4; ++ct) {
      #pragma unroll
      for (int mt = 0; mt < 2; ++mt) {
        f32x4 o = *(const f32x4*)&red[region + ((ct * 2 + mt) * 64 + lane) * 4];
        o += (mt == 0) ? acc[ct] : acc2[ct];
        #pragma unroll
        for (int r = 0; r < 4; ++r) {
          const int c = cq * 64 + ct * 16 + h * 4 + r;
          const size_t idx = (size_t)c * 4096 + (mbase + mt * 16 + r16);
          ob[idx] = gm * o[r] + xb[idx];
        }
      }
    }
  }
}

extern "C" void kernel_launch(void* const* d_in, const int* in_sizes, int n_in,
                              void* d_out, int out_size, void* d_ws, size_t ws_size,
                              hipStream_t stream) {
  const float* x     = (const float*)d_in[0];
  const float* fw    = (const float*)d_in[1];
  const float* fb    = (const float*)d_in[2];
  const float* gw    = (const float*)d_in[3];
  const float* gb    = (const float*)d_in[4];
  const float* hw    = (const float*)d_in[5];
  const float* hb    = (const float*)d_in[6];
  const float* gamma = (const float*)d_in[7];
  float* out = (float*)d_out;

  char* wsb = (char*)d_ws;
  __bf16* fgT = (__bf16*)(wsb);
  __bf16* hv  = (__bf16*)(wsb + 2097152);
  float*  Lp  = (float*) (wsb + 10485760);

  k_proj<<<dim3(256), dim3(512), 0, stream>>>(fw, gw, hw, x, fb, gb, hb, fgT, hv);
  k_pass1<<<dim3(1024), dim3(256), 0, stream>>>(fgT, Lp);
  k_wdiv<<<dim3(256), dim3(256), 0, stream>>>(hv, Lp);
  k_pass2<<<dim3(1024), dim3(256), 0, stream>>>(fgT, hv, x, gamma, out);
}